// Round 1
// baseline (81.578 us; speedup 1.0000x reference)
//
#include <hip/hip_runtime.h>

#define W_ 8192
#define NBATCH 2048
#define TB 8
#define CCH 512
#define NCH (W_/CCH)
#define NT 1024

typedef unsigned short u16_t;
typedef _Float16 h2v __attribute__((ext_vector_type(2)));

__device__ __forceinline__ u16_t f2h(float x){ _Float16 h=(_Float16)x; return __builtin_bit_cast(u16_t,h); }
__device__ __forceinline__ float h2f(u16_t u){ return (float)__builtin_bit_cast(_Float16,u); }
__device__ __forceinline__ unsigned pk2(float a,float b){ return (unsigned)f2h(a)|((unsigned)f2h(b)<<16); }
__device__ __forceinline__ float dot2u(unsigned a,unsigned b,float c){
#if __has_builtin(__builtin_amdgcn_fdot2)
  return __builtin_amdgcn_fdot2(__builtin_bit_cast(h2v,a),__builtin_bit_cast(h2v,b),c,false);
#else
  h2v ha=__builtin_bit_cast(h2v,a), hb=__builtin_bit_cast(h2v,b);
  return c+(float)ha[0]*(float)hb[0]+(float)ha[1]*(float)hb[1];
#endif
}
__device__ __forceinline__ float softplusf(float x){ return fmaxf(x,0.f)+log1pf(expf(-fabsf(x))); }

// Pack tables: per w, 24 f16: [abs0..7, cb0..7, cb8, ray, 0 x6]  (48B, 16B-aligned rows)
__global__ void doas_pack(const float* __restrict__ absn, const float* __restrict__ cbn,
                          const float* __restrict__ ray, u16_t* __restrict__ T){
  int w = blockIdx.x*256 + threadIdx.x;
  if (w >= W_) return;
  u16_t v[24];
  #pragma unroll
  for (int g=0; g<8; ++g) v[g] = f2h(absn[g*W_+w]);
  #pragma unroll
  for (int g=0; g<9; ++g) v[8+g] = f2h(cbn[g*W_+w]);
  v[17] = f2h(ray[w]);
  #pragma unroll
  for (int i=18;i<24;++i) v[i]=0;
  u16_t* tr = T + w*24;
  #pragma unroll
  for (int i=0;i<24;++i) tr[i] = v[i];
}

template<int PACKED>
__global__ __launch_bounds__(NT, 1)
void doas_main(const float* __restrict__ gas, const int* __restrict__ iid,
               const float* __restrict__ nuis, const float* __restrict__ air,
               const float* __restrict__ wl, const float* __restrict__ absn,
               const float* __restrict__ cbn, const float* __restrict__ ray,
               const float* __restrict__ emb, const float* __restrict__ w1,
               const float* __restrict__ b1, const float* __restrict__ w2,
               const float* __restrict__ b2, const u16_t* __restrict__ T,
               float* __restrict__ out)
{
  extern __shared__ char smem[];
  u16_t* nlS   = (u16_t*)smem;            // [TB][8192] f16
  u16_t* diffS = nlS + TB*W_;             // [TB][4][256] f16 ring
  u16_t* itpS  = diffS + TB*1024;         // [TB][544] f16 (526 used)
  float* hS    = (float*)(itpS + TB*544); // [TB][64]
  float* pS    = hS + TB*64;              // [TB][8]
  float* scalS = pS + TB*8;               // [TB][32]
  float* wsumS = scalS + TB*32;           // [16]

  const int tid = threadIdx.x;
  const int r0 = blockIdx.x * TB;

  // ---------- setup: per-row MLP ----------
  if (tid < TB*64) {
    int r = tid >> 6, j = tid & 63;
    int id = iid[r0 + r];
    float acc = b1[j];
    const float* nrow = nuis + (size_t)(r0 + r) * 8;
    #pragma unroll
    for (int i = 0; i < 8; ++i) acc = fmaf(nrow[i], w1[i*64 + j], acc);
    const float* erow = emb + (size_t)id * 128;
    for (int i = 0; i < 128; ++i) acc = fmaf(erow[i], w1[(8+i)*64 + j], acc);
    hS[r*64 + j] = 0.5f * acc * (1.0f + erff(acc * 0.70710678118654752f));
  }
  __syncthreads();
  if (tid < TB*7) {
    int r = tid / 7, k = tid % 7;
    float p = b2[k];
    for (int j = 0; j < 64; ++j) p = fmaf(hS[r*64+j], w2[j*7+k], p);
    pS[r*8+k] = p;
  }
  __syncthreads();
  if (tid < TB) {
    int r = tid;
    float p0=pS[r*8+0], p1=pS[r*8+1], p2=pS[r*8+2], p3=pS[r*8+3],
          p4=pS[r*8+4], p5=pS[r*8+5], p6=pS[r*8+6];
    float gainv = softplusf(p0) + 0.001f;
    float offv  = p1;
    float woffv = 0.05f * tanhf(p2);
    float wscv  = 1.0f + 0.005f * tanhf(p3);
    float lsf   = fminf(fmaxf(softplusf(p4) + 0.001f, 0.2f), 5.0f);
    float strv  = (1.0f/(1.0f+expf(-p5))) * 0.05f;
    float nlin  = 0.02f * tanhf(p6);
    nlin = fminf(fmaxf(nlin, -0.04f), 0.04f);
    strv = fminf(fmaxf(strv, 0.0f), 0.2f);
    float iw = 1.0f/(lsf + 1e-6f);
    float ks[15]; float ksum = 0.f;
    #pragma unroll
    for (int k2=0;k2<15;++k2){ float pp=(float)(k2-7)*iw; float e=expf(-0.5f*pp*pp); ks[k2]=e; ksum+=e; }
    float inv = 1.0f/ksum;
    float* sc = scalS + r*32;
    #pragma unroll
    for (int k2=0;k2<15;++k2) sc[k2]=ks[k2]*inv;
    sc[15]=wscv; sc[16]=woffv; sc[17]=gainv; sc[18]=offv; sc[19]=nlin; sc[20]=strv;
    sc[22]=air[r0+r];
    #pragma unroll
    for (int g=0; g<8; ++g) sc[23+g] = gas[(size_t)(r0+r)*8+g];
  }
  __syncthreads();

  // ---------- per-thread row state ----------
  const int r  = tid >> 7;   // 0..7
  const int wi = tid & 127;  // 0..127
  const float* sc = scalS + r*32;
  float kreg[15];
  #pragma unroll
  for (int k2=0;k2<15;++k2) kreg[k2]=sc[k2];
  const float wscale = sc[15], woff = sc[16], gainv = sc[17], offv = sc[18], nlin = sc[19];
  const float am = sc[22];
  float agf[8], gf[8];
  unsigned cpk[9];
  #pragma unroll
  for (int g=0; g<8; ++g){ gf[g]=sc[23+g]; agf[g]=gf[g]*am; }
  #pragma unroll
  for (int q=0;q<4;++q) cpk[q]   = pk2(agf[2*q], agf[2*q+1]);
  #pragma unroll
  for (int q=0;q<4;++q) cpk[4+q] = pk2(gf[2*q],  gf[2*q+1]);
  cpk[8] = pk2(1.0f, am);

  u16_t* drow  = diffS + r*1024;
  u16_t* irow  = itpS  + r*544;
  u16_t* nrow2 = nlS   + r*W_;
  const float INVDW = 8191.0f/100.0f;

  auto do_diff = [&](int s){
    #pragma unroll
    for (int t2=0;t2<2;++t2){
      int off = wi + t2*128;
      int w = s*256 + off;
      float acc;
      if (PACKED){
        const u16_t* tr = T + (size_t)w*24;
        const uint4* q4 = (const uint4*)tr;
        uint4 a = q4[0], bq = q4[1];
        unsigned c8 = ((const unsigned*)tr)[8];
        acc = 0.f;
        acc = dot2u(a.x, cpk[0], acc); acc = dot2u(a.y, cpk[1], acc);
        acc = dot2u(a.z, cpk[2], acc); acc = dot2u(a.w, cpk[3], acc);
        acc = dot2u(bq.x, cpk[4], acc); acc = dot2u(bq.y, cpk[5], acc);
        acc = dot2u(bq.z, cpk[6], acc); acc = dot2u(c8,  cpk[8], acc);
        acc = dot2u(bq.w, cpk[7], acc);
      } else {
        acc = am * ray[w];
        #pragma unroll
        for (int g=0; g<8; ++g) acc = fmaf(agf[g], absn[g*W_+w], acc);
        #pragma unroll
        for (int g=0; g<8; ++g) acc = fmaf(gf[g], cbn[g*W_+w], acc);
        acc += cbn[8*W_+w];
      }
      drow[((s&3)<<8) + off] = f2h(acc);
    }
  };

  // prologue: diff subchunks 0..2  (covers indices 0..767)
  do_diff(0); do_diff(1); do_diff(2);

  float accsum = 0.f;

  for (int c = 0; c < NCH; ++c) {
    const int cs = c * CCH;
    if (c >= 1) {
      int s1 = 2*c+1, s2 = 2*c+2;
      if (s1 <= 31) do_diff(s1);
      if (s2 <= 31) do_diff(s2);
    }
    __syncthreads();
    // interp fill for global indices [cs-7, cs+519)
    #pragma unroll
    for (int it = 0; it < 5; ++it) {
      int jj = wi + it*128;
      if (jj < CCH + 14) {
        int j = cs - 7 + jj;
        int jc = min(max(j, 0), W_-1);
        float wq = fmaf(wl[jc], wscale, woff);
        float pos = (wq - 300.0f) * INVDW;
        pos = fminf(fmaxf(pos, 0.0f), 8191.0f);
        int i0 = (int)pos; i0 = min(i0, W_-2);
        float fr = pos - (float)i0;
        int i1 = i0 + 1;
        float d0 = h2f(drow[((i0>>8)&3)*256 + (i0&255)]);
        float d1 = h2f(drow[((i1>>8)&3)*256 + (i1&255)]);
        irow[jj] = f2h(fmaf(fr, d1-d0, d0));
      }
    }
    __syncthreads();
    // conv(15) + exp + post + nl ; thread owns 4 consecutive outputs
    {
      const unsigned* ip = (const unsigned*)irow;
      int b0 = wi*4;
      float wv[18];
      #pragma unroll
      for (int m=0;m<9;++m){
        unsigned u = ip[(b0>>1) + m];
        wv[2*m]   = h2f((u16_t)(u & 0xffffu));
        wv[2*m+1] = h2f((u16_t)(u >> 16));
      }
      float nlv4[4];
      #pragma unroll
      for (int j=0;j<4;++j){
        float cv = 0.f;
        #pragma unroll
        for (int k2=0;k2<15;++k2) cv = fmaf(wv[j+k2], kreg[k2], cv);
        float counts = __expf(-cv);
        float post = fmaf(gainv, counts, offv);
        float nlv = fmaf(nlin*post, post, post);
        accsum += nlv;
        nlv4[j] = nlv;
      }
      uint2 pkd = make_uint2(pk2(nlv4[0], nlv4[1]), pk2(nlv4[2], nlv4[3]));
      *((uint2*)(nrow2 + cs + b0)) = pkd;
    }
  }

  // ---------- row mean ----------
  float s = accsum;
  #pragma unroll
  for (int off = 32; off >= 1; off >>= 1) s += __shfl_down(s, off);
  if ((tid & 63) == 0) wsumS[tid >> 6] = s;
  __syncthreads();
  if (tid < TB) scalS[tid*32 + 21] = (wsumS[2*tid] + wsumS[2*tid+1]) * (1.0f/8192.0f);
  __syncthreads();

  // ---------- final write ----------
  {
    const float strv = sc[20];
    const float meanv = sc[21];
    const float a = 1.0f - strv;
    const float bb = strv * meanv;
    float* orow = out + (size_t)(r0 + r) * W_;
    const unsigned* np = (const unsigned*)nrow2;
    #pragma unroll 4
    for (int it = 0; it < 32; ++it) {
      int w2i = wi + it*128;
      unsigned u = np[w2i];
      float v0 = fmaf(a, h2f((u16_t)(u & 0xffffu)), bb);
      float v1 = fmaf(a, h2f((u16_t)(u >> 16)), bb);
      ((float2*)orow)[w2i] = make_float2(v0, v1);
    }
  }
}

extern "C" void kernel_launch(void* const* d_in, const int* in_sizes, int n_in,
                              void* d_out, int out_size, void* d_ws, size_t ws_size,
                              hipStream_t stream) {
  const float* gas  = (const float*)d_in[0];
  const int*   iid  = (const int*)d_in[1];
  const float* nuis = (const float*)d_in[2];
  const float* air  = (const float*)d_in[3];
  const float* wl   = (const float*)d_in[4];
  const float* absn = (const float*)d_in[5];
  const float* cbn  = (const float*)d_in[6];
  const float* ray  = (const float*)d_in[7];
  const float* emb  = (const float*)d_in[8];
  const float* w1   = (const float*)d_in[9];
  const float* b1   = (const float*)d_in[10];
  const float* w2   = (const float*)d_in[11];
  const float* b2   = (const float*)d_in[12];
  float* out = (float*)d_out;
  (void)in_sizes; (void)n_in; (void)out_size;

  const size_t ldsBytes = (size_t)TB*W_*2 + (size_t)TB*1024*2 + (size_t)TB*544*2
                        + (size_t)TB*64*4 + (size_t)TB*8*4 + (size_t)TB*32*4 + 16*4;
  const size_t packBytes = (size_t)W_ * 24 * sizeof(u16_t);

  if (ws_size >= packBytes) {
    u16_t* T = (u16_t*)d_ws;
    hipLaunchKernelGGL(doas_pack, dim3(W_/256), dim3(256), 0, stream, absn, cbn, ray, T);
    hipFuncSetAttribute(reinterpret_cast<const void*>(&doas_main<1>),
                        hipFuncAttributeMaxDynamicSharedMemorySize, (int)ldsBytes);
    hipLaunchKernelGGL((doas_main<1>), dim3(NBATCH/TB), dim3(NT), ldsBytes, stream,
                       gas, iid, nuis, air, wl, absn, cbn, ray, emb, w1, b1, w2, b2, T, out);
  } else {
    hipFuncSetAttribute(reinterpret_cast<const void*>(&doas_main<0>),
                        hipFuncAttributeMaxDynamicSharedMemorySize, (int)ldsBytes);
    hipLaunchKernelGGL((doas_main<0>), dim3(NBATCH/TB), dim3(NT), ldsBytes, stream,
                       gas, iid, nuis, air, wl, absn, cbn, ray, emb, w1, b1, w2, b2,
                       (const u16_t*)nullptr, out);
  }
}

// Round 2
// 80.817 us; speedup vs baseline: 1.0094x; 1.0094x over previous
//
#include <hip/hip_runtime.h>

#define W_ 8192
#define NBATCH 2048
#define TB 4
#define NT 512
#define CCH 1024
#define NCH 8
#define RING 2048
#define IRW 1040   // 1038 used + pad (row stride 2080 B, 16B aligned)

typedef unsigned short u16_t;
typedef _Float16 h2v __attribute__((ext_vector_type(2)));

__device__ __forceinline__ u16_t f2h(float x){ _Float16 h=(_Float16)x; return __builtin_bit_cast(u16_t,h); }
__device__ __forceinline__ float h2f(u16_t u){ return (float)__builtin_bit_cast(_Float16,u); }
__device__ __forceinline__ unsigned pk2(float a,float b){ return (unsigned)f2h(a)|((unsigned)f2h(b)<<16); }
__device__ __forceinline__ float dot2u(unsigned a,unsigned b,float c){
#if __has_builtin(__builtin_amdgcn_fdot2)
  return __builtin_amdgcn_fdot2(__builtin_bit_cast(h2v,a),__builtin_bit_cast(h2v,b),c,false);
#else
  h2v ha=__builtin_bit_cast(h2v,a), hb=__builtin_bit_cast(h2v,b);
  return c+(float)ha[0]*(float)hb[0]+(float)ha[1]*(float)hb[1];
#endif
}
__device__ __forceinline__ unsigned alignb(unsigned hi, unsigned lo){
#if __has_builtin(__builtin_amdgcn_alignbit)
  return __builtin_amdgcn_alignbit(hi, lo, 16);
#else
  return (lo >> 16) | (hi << 16);
#endif
}
__device__ __forceinline__ float softplusf(float x){ return fmaxf(x,0.f)+log1pf(expf(-fabsf(x))); }

// Pack tables: per w, 24 f16: [abs0..7, cb0..7, cb8, ray, 0 x6]  (48B rows, 16B aligned)
__global__ void doas_pack(const float* __restrict__ absn, const float* __restrict__ cbn,
                          const float* __restrict__ ray, u16_t* __restrict__ T){
  int w = blockIdx.x*256 + threadIdx.x;
  if (w >= W_) return;
  u16_t v[24];
  #pragma unroll
  for (int g=0; g<8; ++g) v[g] = f2h(absn[g*W_+w]);
  #pragma unroll
  for (int g=0; g<9; ++g) v[8+g] = f2h(cbn[g*W_+w]);
  v[17] = f2h(ray[w]);
  #pragma unroll
  for (int i=18;i<24;++i) v[i]=0;
  u16_t* tr = T + w*24;
  #pragma unroll
  for (int i=0;i<24;++i) tr[i] = v[i];
}

template<int PACKED>
__global__ __launch_bounds__(NT, 4)
void doas_main(const float* __restrict__ gas, const int* __restrict__ iid,
               const float* __restrict__ nuis, const float* __restrict__ air,
               const float* __restrict__ wl, const float* __restrict__ absn,
               const float* __restrict__ cbn, const float* __restrict__ ray,
               const float* __restrict__ emb, const float* __restrict__ w1,
               const float* __restrict__ b1, const float* __restrict__ w2,
               const float* __restrict__ b2, const u16_t* __restrict__ T,
               float* __restrict__ out)
{
  extern __shared__ char smem[];
  float* ringF = (float*)smem;                               // [TB][2052] f32 ring (2048 + seam dup)
  u16_t* irowS = (u16_t*)(smem + TB*2052*4);                 // [TB][IRW] f16
  float* hS    = (float*)(smem + TB*2052*4 + TB*IRW*2);      // [TB][64]
  float* pS    = hS + TB*64;                                 // [TB][8]
  float* scalS = pS + TB*8;                                  // [TB][32]
  float* wsumS = scalS + TB*32;                              // [NT/64]

  const int tid = threadIdx.x;
  const int r0 = blockIdx.x * TB;

  // ---------- setup: per-row MLP ----------
  if (tid < TB*64) {
    int r = tid >> 6, j = tid & 63;
    int id = iid[r0 + r];
    float acc = b1[j];
    const float* nrow = nuis + (size_t)(r0 + r) * 8;
    #pragma unroll
    for (int i = 0; i < 8; ++i) acc = fmaf(nrow[i], w1[i*64 + j], acc);
    const float* erow = emb + (size_t)id * 128;
    for (int i = 0; i < 128; ++i) acc = fmaf(erow[i], w1[(8+i)*64 + j], acc);
    hS[r*64 + j] = 0.5f * acc * (1.0f + erff(acc * 0.70710678118654752f));
  }
  __syncthreads();
  if (tid < TB*7) {
    int r = tid / 7, k = tid % 7;
    float p = b2[k];
    for (int j = 0; j < 64; ++j) p = fmaf(hS[r*64+j], w2[j*7+k], p);
    pS[r*8+k] = p;
  }
  __syncthreads();
  if (tid < TB) {
    int r = tid;
    float p0=pS[r*8+0], p1=pS[r*8+1], p2=pS[r*8+2], p3=pS[r*8+3],
          p4=pS[r*8+4], p5=pS[r*8+5], p6=pS[r*8+6];
    float gainv = softplusf(p0) + 0.001f;
    float offv  = p1;
    float woffv = 0.05f * tanhf(p2);
    float wscv  = 1.0f + 0.005f * tanhf(p3);
    float lsf   = fminf(fmaxf(softplusf(p4) + 0.001f, 0.2f), 5.0f);
    float strv  = (1.0f/(1.0f+expf(-p5))) * 0.05f;
    float nlin  = 0.02f * tanhf(p6);
    nlin = fminf(fmaxf(nlin, -0.04f), 0.04f);
    strv = fminf(fmaxf(strv, 0.0f), 0.2f);
    float iw = 1.0f/(lsf + 1e-6f);
    float ks[15]; float ksum = 0.f;
    #pragma unroll
    for (int k2=0;k2<15;++k2){ float pp=(float)(k2-7)*iw; float e=expf(-0.5f*pp*pp); ks[k2]=e; ksum+=e; }
    float inv = 1.0f/ksum;
    float* sc = scalS + r*32;
    #pragma unroll
    for (int k2=0;k2<15;++k2) sc[k2]=ks[k2]*inv;
    sc[15]=wscv; sc[16]=woffv; sc[17]=gainv; sc[18]=offv; sc[19]=nlin; sc[20]=strv;
    sc[22]=air[r0+r];
    #pragma unroll
    for (int g=0; g<8; ++g) sc[23+g] = gas[(size_t)(r0+r)*8+g];
  }
  __syncthreads();

  // ---------- per-thread row state ----------
  const int r  = tid >> 7;   // 0..TB-1
  const int wi = tid & 127;  // 0..127
  const float* sc = scalS + r*32;
  unsigned krp[8];
  #pragma unroll
  for (int m=0;m<7;++m) krp[m] = pk2(sc[2*m], sc[2*m+1]);
  krp[7] = pk2(sc[14], 0.0f);
  const float wscale = sc[15], woff = sc[16], gainv = sc[17], offv = sc[18], nlin = sc[19];
  const float am = sc[22];
  const float posoff = (300.0f*(wscale - 1.0f) + woff) * (8191.0f/100.0f);
  float agf[8], gf[8];
  unsigned cpk[9];
  #pragma unroll
  for (int g=0; g<8; ++g){ gf[g]=sc[23+g]; agf[g]=gf[g]*am; }
  #pragma unroll
  for (int q=0;q<4;++q) cpk[q]   = pk2(agf[2*q], agf[2*q+1]);
  #pragma unroll
  for (int q=0;q<4;++q) cpk[4+q] = pk2(gf[2*q],  gf[2*q+1]);
  cpk[8] = pk2(1.0f, am);

  float* ring = ringF + r*2052;
  u16_t* irow = irowS + r*IRW;
  // zero the 2 tail entries of irow once (read by conv's last b128, weight 0 —
  // but garbage bits could be NaN and 0*NaN = NaN in dot2)
  if (wi == 0) ((unsigned*)irow)[519] = 0;

  auto do_diff = [&](int s){
    const int off = 2*wi;
    const int w = s*256 + off;
    float a0, a1;
    if (PACKED){
      const unsigned* tr = (const unsigned*)(T + (size_t)w*24);
      const uint4* q4 = (const uint4*)tr;
      uint4 A0 = q4[0], B0 = q4[1];
      unsigned c80 = tr[8];
      uint4 A1 = q4[3], B1 = q4[4];
      unsigned c81 = tr[20];
      float acc = 0.f;
      acc = dot2u(A0.x, cpk[0], acc); acc = dot2u(A0.y, cpk[1], acc);
      acc = dot2u(A0.z, cpk[2], acc); acc = dot2u(A0.w, cpk[3], acc);
      acc = dot2u(B0.x, cpk[4], acc); acc = dot2u(B0.y, cpk[5], acc);
      acc = dot2u(B0.z, cpk[6], acc); acc = dot2u(B0.w, cpk[7], acc);
      a0  = dot2u(c80,  cpk[8], acc);
      acc = 0.f;
      acc = dot2u(A1.x, cpk[0], acc); acc = dot2u(A1.y, cpk[1], acc);
      acc = dot2u(A1.z, cpk[2], acc); acc = dot2u(A1.w, cpk[3], acc);
      acc = dot2u(B1.x, cpk[4], acc); acc = dot2u(B1.y, cpk[5], acc);
      acc = dot2u(B1.z, cpk[6], acc); acc = dot2u(B1.w, cpk[7], acc);
      a1  = dot2u(c81,  cpk[8], acc);
    } else {
      float aa[2];
      #pragma unroll
      for (int u=0; u<2; ++u){
        int ww = w + u;
        float acc = am * ray[ww];
        #pragma unroll
        for (int g=0; g<8; ++g) acc = fmaf(agf[g], absn[g*W_+ww], acc);
        #pragma unroll
        for (int g=0; g<8; ++g) acc = fmaf(gf[g], cbn[g*W_+ww], acc);
        acc += cbn[8*W_+ww];
        aa[u] = acc;
      }
      a0 = aa[0]; a1 = aa[1];
    }
    const int p = w & (RING-1);
    *(float2*)(ring + p) = make_float2(a0, a1);
    if (p == 0) ring[RING] = a0;   // seam duplicate for read-pair across wrap
  };

  // prologue: subchunks 0..4 cover indices 0..1279 (chunk 0 needs up to ~1198)
  do_diff(0); do_diff(1); do_diff(2); do_diff(3); do_diff(4);

  float accsum = 0.f;
  unsigned nlp[NCH][4];

  #pragma unroll
  for (int c = 0; c < NCH; ++c) {
    const int cs = c * CCH;
    if (c >= 1) {
      #pragma unroll
      for (int ss = 1; ss <= 4; ++ss) {
        int s = 4*c + ss;
        if (s < 32) do_diff(s);
      }
    }
    __syncthreads();
    // interp fill: irow[jj] = warped diff at global index cs-7+jj, jj in [0,1038)
    #pragma unroll
    for (int it = 0; it < 5; ++it) {
      int jj = it*256 + 2*wi;
      if (jj < CCH + 14) {
        float v2[2];
        #pragma unroll
        for (int u=0; u<2; ++u){
          int j = cs - 7 + jj + u;
          int jc = min(max(j, 0), W_-1);
          float pos = fmaf((float)jc, wscale, posoff);
          pos = fminf(fmaxf(pos, 0.0f), 8191.0f);
          int i0 = (int)pos; i0 = min(i0, W_-2);
          float fr = pos - (float)i0;
          int p = i0 & (RING-1);
          float d0 = ring[p], d1 = ring[p+1];
          v2[u] = fmaf(fr, d1-d0, d0);
        }
        ((unsigned*)irow)[jj>>1] = pk2(v2[0], v2[1]);
      }
    }
    __syncthreads();
    // conv(15) + exp + post + nl ; thread owns 8 consecutive outputs
    {
      const uint4* qp = (const uint4*)irow;
      uint4 A = qp[wi], Bq = qp[wi+1], Cq = qp[wi+2];
      unsigned q[12] = {A.x,A.y,A.z,A.w, Bq.x,Bq.y,Bq.z,Bq.w, Cq.x,Cq.y,Cq.z,Cq.w};
      unsigned sh[11];
      #pragma unroll
      for (int m=0;m<11;++m) sh[m] = alignb(q[m+1], q[m]);
      float nlv[8];
      #pragma unroll
      for (int j=0;j<8;++j){
        float cv = 0.f;
        #pragma unroll
        for (int m=0;m<8;++m){
          unsigned src = (j & 1) ? sh[(j>>1)+m] : q[(j>>1)+m];
          cv = dot2u(src, krp[m], cv);
        }
        float counts = __expf(-cv);
        float post = fmaf(gainv, counts, offv);
        float v = fmaf(nlin*post, post, post);
        accsum += v;
        nlv[j] = v;
      }
      nlp[c][0] = pk2(nlv[0], nlv[1]);
      nlp[c][1] = pk2(nlv[2], nlv[3]);
      nlp[c][2] = pk2(nlv[4], nlv[5]);
      nlp[c][3] = pk2(nlv[6], nlv[7]);
    }
  }

  // ---------- row mean ----------
  float s = accsum;
  #pragma unroll
  for (int off2 = 32; off2 >= 1; off2 >>= 1) s += __shfl_down(s, off2);
  if ((tid & 63) == 0) wsumS[tid >> 6] = s;
  __syncthreads();
  if (tid < TB) scalS[tid*32 + 21] = (wsumS[2*tid] + wsumS[2*tid+1]) * (1.0f/8192.0f);
  __syncthreads();

  // ---------- final write ----------
  {
    const float strv = sc[20];
    const float meanv = sc[21];
    const float aa = 1.0f - strv;
    const float bb = strv * meanv;
    float* orow = out + (size_t)(r0 + r) * W_;
    #pragma unroll
    for (int c = 0; c < NCH; ++c) {
      unsigned u0 = nlp[c][0], u1 = nlp[c][1], u2 = nlp[c][2], u3 = nlp[c][3];
      float4 o0, o1;
      o0.x = fmaf(aa, h2f((u16_t)(u0 & 0xffffu)), bb);
      o0.y = fmaf(aa, h2f((u16_t)(u0 >> 16)),     bb);
      o0.z = fmaf(aa, h2f((u16_t)(u1 & 0xffffu)), bb);
      o0.w = fmaf(aa, h2f((u16_t)(u1 >> 16)),     bb);
      o1.x = fmaf(aa, h2f((u16_t)(u2 & 0xffffu)), bb);
      o1.y = fmaf(aa, h2f((u16_t)(u2 >> 16)),     bb);
      o1.z = fmaf(aa, h2f((u16_t)(u3 & 0xffffu)), bb);
      o1.w = fmaf(aa, h2f((u16_t)(u3 >> 16)),     bb);
      float* dst = orow + c*CCH + 8*wi;
      *(float4*)(dst)     = o0;
      *(float4*)(dst + 4) = o1;
    }
  }
}

extern "C" void kernel_launch(void* const* d_in, const int* in_sizes, int n_in,
                              void* d_out, int out_size, void* d_ws, size_t ws_size,
                              hipStream_t stream) {
  const float* gas  = (const float*)d_in[0];
  const int*   iid  = (const int*)d_in[1];
  const float* nuis = (const float*)d_in[2];
  const float* air  = (const float*)d_in[3];
  const float* wl   = (const float*)d_in[4];
  const float* absn = (const float*)d_in[5];
  const float* cbn  = (const float*)d_in[6];
  const float* ray  = (const float*)d_in[7];
  const float* emb  = (const float*)d_in[8];
  const float* w1   = (const float*)d_in[9];
  const float* b1   = (const float*)d_in[10];
  const float* w2   = (const float*)d_in[11];
  const float* b2   = (const float*)d_in[12];
  float* out = (float*)d_out;
  (void)in_sizes; (void)n_in; (void)out_size;

  const size_t ldsBytes = (size_t)TB*2052*4 + (size_t)TB*IRW*2
                        + (size_t)TB*64*4 + (size_t)TB*8*4 + (size_t)TB*32*4 + (NT/64)*4;
  const size_t packBytes = (size_t)W_ * 24 * sizeof(u16_t);

  if (ws_size >= packBytes) {
    u16_t* T = (u16_t*)d_ws;
    hipLaunchKernelGGL(doas_pack, dim3(W_/256), dim3(256), 0, stream, absn, cbn, ray, T);
    hipFuncSetAttribute(reinterpret_cast<const void*>(&doas_main<1>),
                        hipFuncAttributeMaxDynamicSharedMemorySize, (int)ldsBytes);
    hipLaunchKernelGGL((doas_main<1>), dim3(NBATCH/TB), dim3(NT), ldsBytes, stream,
                       gas, iid, nuis, air, wl, absn, cbn, ray, emb, w1, b1, w2, b2, T, out);
  } else {
    hipFuncSetAttribute(reinterpret_cast<const void*>(&doas_main<0>),
                        hipFuncAttributeMaxDynamicSharedMemorySize, (int)ldsBytes);
    hipLaunchKernelGGL((doas_main<0>), dim3(NBATCH/TB), dim3(NT), ldsBytes, stream,
                       gas, iid, nuis, air, wl, absn, cbn, ray, emb, w1, b1, w2, b2,
                       (const u16_t*)nullptr, out);
  }
}

// Round 3
// 57.553 us; speedup vs baseline: 1.4174x; 1.4042x over previous
//
#include <hip/hip_runtime.h>

#define W_ 8192
#define NBATCH 2048
#define TB 4
#define NT 512
#define CCH 1024
#define NCH 8
#define NSUB 16
#define RING 2048
#define RSTR 2052
#define IRW 1040

typedef unsigned short u16_t;
typedef _Float16 h2v __attribute__((ext_vector_type(2)));

__device__ __forceinline__ u16_t f2h(float x){ _Float16 h=(_Float16)x; return __builtin_bit_cast(u16_t,h); }
__device__ __forceinline__ float h2f(u16_t u){ return (float)__builtin_bit_cast(_Float16,u); }
__device__ __forceinline__ unsigned pk2(float a,float b){ return (unsigned)f2h(a)|((unsigned)f2h(b)<<16); }
__device__ __forceinline__ float dot2u(unsigned a,unsigned b,float c){
#if __has_builtin(__builtin_amdgcn_fdot2)
  return __builtin_amdgcn_fdot2(__builtin_bit_cast(h2v,a),__builtin_bit_cast(h2v,b),c,false);
#else
  h2v ha=__builtin_bit_cast(h2v,a), hb=__builtin_bit_cast(h2v,b);
  return c+(float)ha[0]*(float)hb[0]+(float)ha[1]*(float)hb[1];
#endif
}
__device__ __forceinline__ unsigned pkrtz(float a,float b){
#if __has_builtin(__builtin_amdgcn_cvt_pkrtz)
  return __builtin_bit_cast(unsigned, __builtin_amdgcn_cvt_pkrtz(a,b));
#else
  return pk2(a,b);
#endif
}
__device__ __forceinline__ float softplusf(float x){ return fmaxf(x,0.f)+log1pf(expf(-fabsf(x))); }

// SoA-of-pairs pack: Tp[q*W_+w] = f16pair q of element w.
// q=0..3: (abs[2q],abs[2q+1]) ; q=4..7: (cb[2(q-4)],cb[2(q-4)+1]) ; q=8: (cb8, ray)
__global__ void doas_pack(const float* __restrict__ absn, const float* __restrict__ cbn,
                          const float* __restrict__ ray, unsigned* __restrict__ Tp){
  int w = blockIdx.x*256 + threadIdx.x;
  if (w >= W_) return;
  #pragma unroll
  for (int q=0;q<4;++q) Tp[q*W_+w]     = pk2(absn[(2*q)*W_+w], absn[(2*q+1)*W_+w]);
  #pragma unroll
  for (int q=0;q<4;++q) Tp[(4+q)*W_+w] = pk2(cbn[(2*q)*W_+w],  cbn[(2*q+1)*W_+w]);
  Tp[8*W_+w] = pk2(cbn[8*W_+w], ray[w]);
}

template<int PACKED>
__global__ __launch_bounds__(NT, 4)
void doas_main(const float* __restrict__ gas, const int* __restrict__ iid,
               const float* __restrict__ nuis, const float* __restrict__ air,
               const float* __restrict__ wl, const float* __restrict__ absn,
               const float* __restrict__ cbn, const float* __restrict__ ray,
               const float* __restrict__ emb, const float* __restrict__ w1,
               const float* __restrict__ b1, const float* __restrict__ w2,
               const float* __restrict__ b2, const unsigned* __restrict__ Tp,
               float* __restrict__ out)
{
  extern __shared__ char smem[];
  float* ringF = (float*)smem;                               // [TB][RSTR] f32
  float* irowS = (float*)(smem + TB*RSTR*4);                 // [TB][IRW] f32
  float* hS    = (float*)(smem + TB*RSTR*4 + TB*IRW*4);      // [TB][64]
  float* pS    = hS + TB*64;                                 // [TB][8]
  float* scalS = pS + TB*8;                                  // [TB][32]
  float* wsumS = scalS + TB*32;                              // [NT/64]

  const int tid = threadIdx.x;
  const int r0 = blockIdx.x * TB;

  // ---------- setup: per-row MLP ----------
  if (tid < TB*64) {
    int rr = tid >> 6, j = tid & 63;
    int id = iid[r0 + rr];
    float acc = b1[j];
    const float* nrow = nuis + (size_t)(r0 + rr) * 8;
    #pragma unroll
    for (int i = 0; i < 8; ++i) acc = fmaf(nrow[i], w1[i*64 + j], acc);
    const float* erow = emb + (size_t)id * 128;
    for (int i = 0; i < 128; ++i) acc = fmaf(erow[i], w1[(8+i)*64 + j], acc);
    hS[rr*64 + j] = 0.5f * acc * (1.0f + erff(acc * 0.70710678118654752f));
  }
  __syncthreads();
  if (tid < TB*7) {
    int rr = tid / 7, k = tid % 7;
    float p = b2[k];
    for (int j = 0; j < 64; ++j) p = fmaf(hS[rr*64+j], w2[j*7+k], p);
    pS[rr*8+k] = p;
  }
  __syncthreads();
  if (tid < TB) {
    int rr = tid;
    float p0=pS[rr*8+0], p1=pS[rr*8+1], p2=pS[rr*8+2], p3=pS[rr*8+3],
          p4=pS[rr*8+4], p5=pS[rr*8+5], p6=pS[rr*8+6];
    float gainv = softplusf(p0) + 0.001f;
    float offv  = p1;
    float woffv = 0.05f * tanhf(p2);
    float wscv  = 1.0f + 0.005f * tanhf(p3);
    float lsf   = fminf(fmaxf(softplusf(p4) + 0.001f, 0.2f), 5.0f);
    float strv  = (1.0f/(1.0f+expf(-p5))) * 0.05f;
    float nlin  = 0.02f * tanhf(p6);
    nlin = fminf(fmaxf(nlin, -0.04f), 0.04f);
    strv = fminf(fmaxf(strv, 0.0f), 0.2f);
    float iw = 1.0f/(lsf + 1e-6f);
    float ks[15]; float ksum = 0.f;
    #pragma unroll
    for (int k2=0;k2<15;++k2){ float pp=(float)(k2-7)*iw; float e=expf(-0.5f*pp*pp); ks[k2]=e; ksum+=e; }
    float inv = 1.0f/ksum;
    float* sc = scalS + rr*32;
    #pragma unroll
    for (int k2=0;k2<15;++k2) sc[k2]=ks[k2]*inv;
    sc[15]=wscv; sc[16]=woffv; sc[17]=gainv; sc[18]=offv; sc[19]=nlin; sc[20]=strv;
    sc[22]=air[r0+rr];
    #pragma unroll
    for (int g=0; g<8; ++g) sc[23+g] = gas[(size_t)(r0+rr)*8+g];
  }
  __syncthreads();

  // ---------- block-uniform diff coefficients -> SGPRs ----------
  unsigned csg[TB][9];
  #pragma unroll
  for (int rr=0; rr<TB; ++rr){
    const float* scr = scalS + rr*32;
    float amr = scr[22];
    #pragma unroll
    for (int q=0;q<4;++q)
      csg[rr][q] = (unsigned)__builtin_amdgcn_readfirstlane(
          (int)pk2(scr[23+2*q]*amr, scr[23+2*q+1]*amr));
    #pragma unroll
    for (int q=0;q<4;++q)
      csg[rr][4+q] = (unsigned)__builtin_amdgcn_readfirstlane(
          (int)pk2(scr[23+2*q], scr[23+2*q+1]));
    csg[rr][8] = (unsigned)__builtin_amdgcn_readfirstlane((int)pk2(1.0f, amr));
  }

  // ---------- per-thread row state ----------
  const int r  = tid >> 7;   // 0..TB-1
  const int wi = tid & 127;  // 0..127
  const float* sc = scalS + r*32;
  float kw[15];
  #pragma unroll
  for (int k2=0;k2<15;++k2) kw[k2]=sc[k2];
  const float wscale = sc[15], woff = sc[16], gainv = sc[17], offv = sc[18], nlin = sc[19];
  const float posoff = (300.0f*(wscale - 1.0f) + woff) * (8191.0f/100.0f);

  float* ring = ringF + r*RSTR;
  float* irow = irowS + r*IRW;

  // cooperative diff: thread handles element e = s*512+tid for ALL TB rows
  auto do_diff = [&](int s){
    const int e = s*NT + tid;
    float a0=0.f, a1=0.f, a2=0.f, a3=0.f;
    if (PACKED){
      #pragma unroll
      for (int q=0;q<9;++q){
        unsigned d = Tp[q*W_ + e];            // coalesced: 4 lines / wave-inst
        a0 = dot2u(d, csg[0][q], a0);
        a1 = dot2u(d, csg[1][q], a1);
        a2 = dot2u(d, csg[2][q], a2);
        a3 = dot2u(d, csg[3][q], a3);
      }
    } else {
      float av[9][2];
      #pragma unroll
      for (int q=0;q<4;++q){ av[q][0]=absn[(2*q)*W_+e]; av[q][1]=absn[(2*q+1)*W_+e]; }
      #pragma unroll
      for (int q=0;q<4;++q){ av[4+q][0]=cbn[(2*q)*W_+e]; av[4+q][1]=cbn[(2*q+1)*W_+e]; }
      av[8][0]=cbn[8*W_+e]; av[8][1]=ray[e];
      float acc[TB]={0.f,0.f,0.f,0.f};
      #pragma unroll
      for (int rr=0;rr<TB;++rr){
        #pragma unroll
        for (int q=0;q<9;++q){
          acc[rr] = fmaf(h2f((u16_t)(csg[rr][q]&0xffffu)), av[q][0], acc[rr]);
          acc[rr] = fmaf(h2f((u16_t)(csg[rr][q]>>16)),     av[q][1], acc[rr]);
        }
      }
      a0=acc[0]; a1=acc[1]; a2=acc[2]; a3=acc[3];
    }
    const int p = e & (RING-1);
    ringF[0*RSTR+p]=a0; ringF[1*RSTR+p]=a1; ringF[2*RSTR+p]=a2; ringF[3*RSTR+p]=a3;
    if (p == 0){
      ringF[0*RSTR+RING]=a0; ringF[1*RSTR+RING]=a1;
      ringF[2*RSTR+RING]=a2; ringF[3*RSTR+RING]=a3;
    }
  };

  // prologue: subchunks 0..2 cover elements 0..1535 (chunk 0 needs <=1199)
  do_diff(0); do_diff(1); do_diff(2);

  float accsum = 0.f;
  unsigned nlp[NCH][4];

  #pragma unroll
  for (int c = 0; c < NCH; ++c) {
    const int cs = c * CCH;
    const bool eLo = (c == 0), eHi = (c == NCH-1);
    if (c >= 1) {
      if (2*c+1 < NSUB) do_diff(2*c+1);
      if (2*c+2 < NSUB) do_diff(2*c+2);
    }
    __syncthreads();
    // interp fill: irow[k] = warped diff at global index cs-7+k, k in [0,1038)
    #pragma unroll
    for (int it = 0; it < 5; ++it) {
      int jj = it*256 + 2*wi;
      if (jj < CCH + 14) {
        float v2[2];
        #pragma unroll
        for (int u=0; u<2; ++u){
          int j = cs - 7 + jj + u;
          int jc = j;
          if (eLo) jc = max(jc, 0);
          if (eHi) jc = min(jc, W_-1);
          float pos = fmaf((float)jc, wscale, posoff);
          if (eLo) pos = fmaxf(pos, 0.0f);
          if (eHi) pos = fminf(pos, 8191.0f);
          int i0 = (int)pos;
          if (eHi) i0 = min(i0, W_-2);
          float fr = pos - (float)i0;
          int p = i0 & (RING-1);
          float d0 = ring[p], d1 = ring[p+1];
          v2[u] = fmaf(fr, d1-d0, d0);
        }
        *(float2*)(irow + jj) = make_float2(v2[0], v2[1]);
      }
    }
    __syncthreads();
    // conv(15) + exp + post + nl ; thread owns 8 consecutive outputs
    {
      const int b0 = 8*wi;
      const float4* qp = (const float4*)(irow + b0);
      float4 A=qp[0], B=qp[1], C=qp[2], D=qp[3], E=qp[4], F=qp[5];
      float wr[24] = {A.x,A.y,A.z,A.w, B.x,B.y,B.z,B.w, C.x,C.y,C.z,C.w,
                      D.x,D.y,D.z,D.w, E.x,E.y,E.z,E.w, F.x,F.y,F.z,F.w};
      float nlv[8];
      #pragma unroll
      for (int j=0;j<8;++j){
        float cv = 0.f;
        #pragma unroll
        for (int t=0;t<15;++t) cv = fmaf(wr[j+t], kw[t], cv);
        float counts = __expf(-cv);
        float post = fmaf(gainv, counts, offv);
        float v = fmaf(nlin*post, post, post);
        accsum += v;
        nlv[j] = v;
      }
      nlp[c][0] = pkrtz(nlv[0], nlv[1]);
      nlp[c][1] = pkrtz(nlv[2], nlv[3]);
      nlp[c][2] = pkrtz(nlv[4], nlv[5]);
      nlp[c][3] = pkrtz(nlv[6], nlv[7]);
    }
  }

  // ---------- row mean ----------
  float s = accsum;
  #pragma unroll
  for (int off2 = 32; off2 >= 1; off2 >>= 1) s += __shfl_down(s, off2);
  if ((tid & 63) == 0) wsumS[tid >> 6] = s;
  __syncthreads();
  if (tid < TB) scalS[tid*32 + 21] = (wsumS[2*tid] + wsumS[2*tid+1]) * (1.0f/8192.0f);
  __syncthreads();

  // ---------- final write ----------
  {
    const float strv = sc[20];
    const float meanv = sc[21];
    const float aa = 1.0f - strv;
    const float bb = strv * meanv;
    float* orow = out + (size_t)(r0 + r) * W_;
    #pragma unroll
    for (int c = 0; c < NCH; ++c) {
      unsigned u0 = nlp[c][0], u1 = nlp[c][1], u2 = nlp[c][2], u3 = nlp[c][3];
      float4 o0, o1;
      o0.x = fmaf(aa, h2f((u16_t)(u0 & 0xffffu)), bb);
      o0.y = fmaf(aa, h2f((u16_t)(u0 >> 16)),     bb);
      o0.z = fmaf(aa, h2f((u16_t)(u1 & 0xffffu)), bb);
      o0.w = fmaf(aa, h2f((u16_t)(u1 >> 16)),     bb);
      o1.x = fmaf(aa, h2f((u16_t)(u2 & 0xffffu)), bb);
      o1.y = fmaf(aa, h2f((u16_t)(u2 >> 16)),     bb);
      o1.z = fmaf(aa, h2f((u16_t)(u3 & 0xffffu)), bb);
      o1.w = fmaf(aa, h2f((u16_t)(u3 >> 16)),     bb);
      float* dst = orow + c*CCH + 8*wi;
      *(float4*)(dst)     = o0;
      *(float4*)(dst + 4) = o1;
    }
  }
}

extern "C" void kernel_launch(void* const* d_in, const int* in_sizes, int n_in,
                              void* d_out, int out_size, void* d_ws, size_t ws_size,
                              hipStream_t stream) {
  const float* gas  = (const float*)d_in[0];
  const int*   iid  = (const int*)d_in[1];
  const float* nuis = (const float*)d_in[2];
  const float* air  = (const float*)d_in[3];
  const float* wl   = (const float*)d_in[4];
  const float* absn = (const float*)d_in[5];
  const float* cbn  = (const float*)d_in[6];
  const float* ray  = (const float*)d_in[7];
  const float* emb  = (const float*)d_in[8];
  const float* w1   = (const float*)d_in[9];
  const float* b1   = (const float*)d_in[10];
  const float* w2   = (const float*)d_in[11];
  const float* b2   = (const float*)d_in[12];
  float* out = (float*)d_out;
  (void)in_sizes; (void)n_in; (void)out_size; (void)wl;

  const size_t ldsBytes = (size_t)TB*RSTR*4 + (size_t)TB*IRW*4
                        + (size_t)TB*64*4 + (size_t)TB*8*4 + (size_t)TB*32*4 + (NT/64)*4;
  const size_t packBytes = (size_t)9 * W_ * 4;

  if (ws_size >= packBytes) {
    unsigned* Tp = (unsigned*)d_ws;
    hipLaunchKernelGGL(doas_pack, dim3(W_/256), dim3(256), 0, stream, absn, cbn, ray, Tp);
    hipFuncSetAttribute(reinterpret_cast<const void*>(&doas_main<1>),
                        hipFuncAttributeMaxDynamicSharedMemorySize, (int)ldsBytes);
    hipLaunchKernelGGL((doas_main<1>), dim3(NBATCH/TB), dim3(NT), ldsBytes, stream,
                       gas, iid, nuis, air, wl, absn, cbn, ray, emb, w1, b1, w2, b2, Tp, out);
  } else {
    hipFuncSetAttribute(reinterpret_cast<const void*>(&doas_main<0>),
                        hipFuncAttributeMaxDynamicSharedMemorySize, (int)ldsBytes);
    hipLaunchKernelGGL((doas_main<0>), dim3(NBATCH/TB), dim3(NT), ldsBytes, stream,
                       gas, iid, nuis, air, wl, absn, cbn, ray, emb, w1, b1, w2, b2,
                       (const unsigned*)nullptr, out);
  }
}